// Round 10
// baseline (239.819 us; speedup 1.0000x reference)
//
#include <hip/hip_runtime.h>
#include <math.h>

#define H_ 128
#define W_ 160
#define D_ 48
#define C_ 32
#define K27 27
#define HW_ (H_ * W_)
#define DHW_ (D_ * HW_)
#define CHW_ (C_ * HW_)

typedef float f4 __attribute__((ext_vector_type(4)));

// ---------------------------------------------------------------------------
// Projection setup (affine fast path). M(v) = [K(3x3)@E(3x4); 0 0 0 1] is
// affine (E row3 = [0,0,0,1]); inv([[A,b],[0,1]]) = [[A^-1, -A^-1 b],[0,1]].
// For each src view v=1..4 store rot(9)+trans(3) of Mv @ inv(M0).
// ---------------------------------------------------------------------------
__device__ __forceinline__ void build_affine(const float* __restrict__ P, int v,
                                             double A[3][3], double b[3]) {
    const float* E = P + v * 32;
    const float* K = P + v * 32 + 16;
    for (int i = 0; i < 3; i++) {
        for (int j = 0; j < 3; j++) {
            double s = 0.0;
            for (int k = 0; k < 3; k++) s += (double)K[i * 4 + k] * (double)E[k * 4 + j];
            A[i][j] = s;
        }
        double s = 0.0;
        for (int k = 0; k < 3; k++) s += (double)K[i * 4 + k] * (double)E[k * 4 + 3];
        b[i] = s;
    }
}

__device__ void do_proj(const float* __restrict__ P, float* __restrict__ rt) {
    double A0[3][3], b0[3];
    build_affine(P, 0, A0, b0);
    double det = A0[0][0] * (A0[1][1] * A0[2][2] - A0[1][2] * A0[2][1])
               - A0[0][1] * (A0[1][0] * A0[2][2] - A0[1][2] * A0[2][0])
               + A0[0][2] * (A0[1][0] * A0[2][1] - A0[1][1] * A0[2][0]);
    double id = 1.0 / det;
    double Ai[3][3];
    Ai[0][0] = (A0[1][1] * A0[2][2] - A0[1][2] * A0[2][1]) * id;
    Ai[0][1] = (A0[0][2] * A0[2][1] - A0[0][1] * A0[2][2]) * id;
    Ai[0][2] = (A0[0][1] * A0[1][2] - A0[0][2] * A0[1][1]) * id;
    Ai[1][0] = (A0[1][2] * A0[2][0] - A0[1][0] * A0[2][2]) * id;
    Ai[1][1] = (A0[0][0] * A0[2][2] - A0[0][2] * A0[2][0]) * id;
    Ai[1][2] = (A0[0][2] * A0[1][0] - A0[0][0] * A0[1][2]) * id;
    Ai[2][0] = (A0[1][0] * A0[2][1] - A0[1][1] * A0[2][0]) * id;
    Ai[2][1] = (A0[0][1] * A0[2][0] - A0[0][0] * A0[2][1]) * id;
    Ai[2][2] = (A0[0][0] * A0[1][1] - A0[0][1] * A0[1][0]) * id;
    double t0[3];
    for (int i = 0; i < 3; i++)
        t0[i] = -(Ai[i][0] * b0[0] + Ai[i][1] * b0[1] + Ai[i][2] * b0[2]);

    for (int v = 1; v < 5; ++v) {
        double Av[3][3], bv[3];
        build_affine(P, v, Av, bv);
        float* o = rt + (v - 1) * 12;
        for (int i = 0; i < 3; i++) {
            for (int j = 0; j < 3; j++) {
                double s = Av[i][0] * Ai[0][j] + Av[i][1] * Ai[1][j] + Av[i][2] * Ai[2][j];
                o[i * 3 + j] = (float)s;
            }
            o[9 + i] = (float)(Av[i][0] * t0[0] + Av[i][1] * t0[1] +
                               Av[i][2] * t0[2] + bv[i]);
        }
    }
}

// ---------------------------------------------------------------------------
// Kernel 1: LDS-staged transpose [4][C][HW] -> [4][HW][C] for both tensors,
// fully coalesced reads AND writes. 2560 tile-blocks + 1 proj block.
// ---------------------------------------------------------------------------
__global__ void __launch_bounds__(256)
transpose2_kernel(const float* __restrict__ sf, const float* __restrict__ rf,
                  float* __restrict__ so, float* __restrict__ ro,
                  const float* __restrict__ P, float* __restrict__ rt) {
    int blk = blockIdx.x;
    if (blk >= 2560) {
        if (threadIdx.x == 0) do_proj(P, rt);
        return;
    }
    __shared__ float tile[C_][65];
    int t = threadIdx.x;
    int tv = blk / 320;            // 0..7: tensor(2) x view(4)
    int tileI = blk % 320;
    int pixbase = tileI * 64;
    const float* in = (tv < 4) ? sf : rf;
    float* out = (tv < 4) ? so : ro;
    int v = tv & 3;

    int pix = t & 63;
    int cbase = (t >> 6) * 8;
#pragma unroll
    for (int cc = 0; cc < 8; cc++) {
        int c = cbase + cc;
        tile[c][pix] = in[(size_t)v * CHW_ + c * HW_ + pixbase + pix];
    }
    __syncthreads();

    float* obase = out + ((size_t)v * HW_ + pixbase) * C_;
#pragma unroll
    for (int r = 0; r < 2; r++) {
        int i = r * 256 + t;       // f4 index 0..511
        int wpix = i >> 3;
        int c0 = (i & 7) * 4;
        f4 w = {tile[c0][wpix], tile[c0 + 1][wpix], tile[c0 + 2][wpix],
                tile[c0 + 3][wpix]};
        *(f4*)(obase + (size_t)wpix * C_ + c0) = w;
    }
}

// ---------------------------------------------------------------------------
// Kernel 2: one image row (d,y) per block; 3 batches of 64 positions
// (62 outputs + 2 halo each). Small LDS (15.2 KB) for 8 blocks/CU.
//   phase 1: bilinear+ref blend for 8 channels -> accT LDS
//   phase 2: fold channels through conv weights (wave-uniform taps, SGPR
//            weights, 4 partial sums) -> gLDS[27][64]
//   phase 3: per-batch x-shift-add -> 9 planes Gx
// ---------------------------------------------------------------------------
__global__ void __launch_bounds__(256, 8)
warp_fold_x_kernel(const float* __restrict__ srcT,
                   const float* __restrict__ refT,
                   const float* __restrict__ rt,
                   const float* __restrict__ dvals,
                   const float* __restrict__ wreg,
                   float* __restrict__ Gx) {
    __shared__ float accT[8][64][4];   // 8 KB
    __shared__ float gLDS[K27][64];    // 6.9 KB

    int t = threadIdx.x;
    int vox = t >> 2;          // 0..63
    int cgrp = t & 3;          // channel group
    int blk = blockIdx.x;      // 0..6143
    int d = blk >> 7;
    int y = blk & 127;
    float depth = dvals[d];
    float yf = (float)y;
    int rowbase = d * HW_ + y * W_;

#pragma unroll 1
    for (int b = 0; b < 3; b++) {
        int xbase = b * 62 - 1;
        int x = xbase + vox;              // -1 .. 186

        f4 acc0 = (f4){0.f, 0.f, 0.f, 0.f};
        f4 acc1 = (f4){0.f, 0.f, 0.f, 0.f};

        if (x >= 0 && x < W_) {
            float xf = (float)x;
            int pix = y * W_ + x;
#pragma unroll 2
            for (int v = 0; v < 4; v++) {
                const float* m = rt + v * 12;
                float px = fmaf(fmaf(m[0], xf, fmaf(m[1], yf, m[2])), depth, m[9]);
                float py = fmaf(fmaf(m[3], xf, fmaf(m[4], yf, m[5])), depth, m[10]);
                float pz = fmaf(fmaf(m[6], xf, fmaf(m[7], yf, m[8])), depth, m[11]);
                float iz = 1.f / pz;
                px *= iz;
                py *= iz;
                float x0f = floorf(px), y0f = floorf(py);
                float wx = px - x0f, wy = py - y0f;
                int x0 = (int)x0f, y0 = (int)y0f;
                int x1 = x0 + 1, y1 = y0 + 1;

                float w00 = (1.f - wx) * (1.f - wy);
                float w10 = wx * (1.f - wy);
                float w01 = (1.f - wx) * wy;
                float w11 = wx * wy;
                bool vx0 = (x0 >= 0) && (x0 < W_);
                bool vx1 = (x1 >= 0) && (x1 < W_);
                bool vy0 = (y0 >= 0) && (y0 < H_);
                bool vy1 = (y1 >= 0) && (y1 < H_);
                if (!(vx0 && vy0)) w00 = 0.f;
                if (!(vx1 && vy0)) w10 = 0.f;
                if (!(vx0 && vy1)) w01 = 0.f;
                if (!(vx1 && vy1)) w11 = 0.f;
                int cx0 = min(max(x0, 0), W_ - 1);
                int cx1 = min(max(x1, 0), W_ - 1);
                int cy0 = min(max(y0, 0), H_ - 1);
                int cy1 = min(max(y1, 0), H_ - 1);

                const float* sv = srcT + (size_t)v * HW_ * C_ + cgrp * 8;
                const f4* p00 = (const f4*)(sv + (cy0 * W_ + cx0) * C_);
                const f4* p10 = (const f4*)(sv + (cy0 * W_ + cx1) * C_);
                const f4* p01 = (const f4*)(sv + (cy1 * W_ + cx0) * C_);
                const f4* p11 = (const f4*)(sv + (cy1 * W_ + cx1) * C_);
                const f4* pr  = (const f4*)(refT + ((size_t)v * HW_ + pix) * C_ + cgrp * 8);

                f4 a00 = p00[0], b00 = p00[1];
                f4 a10 = p10[0], b10 = p10[1];
                f4 a01 = p01[0], b01 = p01[1];
                f4 a11 = p11[0], b11 = p11[1];
                f4 r0 = pr[0],  r1 = pr[1];

                f4 sv0 = a00 * w00 + a10 * w10 + a01 * w01 + a11 * w11;
                f4 sv1 = b00 * w00 + b10 * w10 + b01 * w01 + b11 * w11;
                acc0 += r0 * sv0;
                acc1 += r1 * sv1;
            }
            acc0 *= 0.25f;
            acc1 *= 0.25f;
        }

        int cq0 = cgrp * 2;
        *(f4*)&accT[cq0][vox][0] = acc0;
        *(f4*)&accT[cq0 + 1][vox][0] = acc1;
        __syncthreads();

        // ---- phase 2: fold channels, wave-uniform tap ranges ----
        int fvox = t & 63;
        int kg = t >> 6;                   // 0..3
        float av[C_];
#pragma unroll
        for (int cq = 0; cq < 8; cq++)
            *(f4*)&av[cq * 4] = *(const f4*)&accT[cq][fvox][0];

        int kstart = kg * 7;
        int kend = min(kstart + 7, K27);
#pragma unroll 1
        for (int k = kstart; k < kend; k++) {
            int ku = __builtin_amdgcn_readfirstlane(k);
            const float* wk = wreg + ku;
            float g0 = 0.f, g1 = 0.f, g2 = 0.f, g3 = 0.f;
#pragma unroll
            for (int cq = 0; cq < 8; cq++) {
                g0 = fmaf(wk[(cq * 4 + 0) * K27], av[cq * 4 + 0], g0);
                g1 = fmaf(wk[(cq * 4 + 1) * K27], av[cq * 4 + 1], g1);
                g2 = fmaf(wk[(cq * 4 + 2) * K27], av[cq * 4 + 2], g2);
                g3 = fmaf(wk[(cq * 4 + 3) * K27], av[cq * 4 + 3], g3);
            }
            gLDS[ku][fvox] = (g0 + g1) + (g2 + g3);
        }
        __syncthreads();

        // ---- phase 3: x-shift-add for this batch -> 9 planes ----
        int xout = b * 62 + t;            // t < 62 lanes participate
        if (t < 62 && xout < W_) {
#pragma unroll
            for (int j = 0; j < 9; j++) {
                float s = gLDS[j * 3 + 0][t] + gLDS[j * 3 + 1][t + 1] +
                          gLDS[j * 3 + 2][t + 2];
                Gx[(size_t)j * DHW_ + rowbase + xout] = s;
            }
        }
        __syncthreads();   // gLDS/accT reuse next batch
    }
}

// ---------------------------------------------------------------------------
// Kernel 3 (fused): gather 9 Gx planes over (d,y) shifts + softmax over D +
// expected depth + windowed confidence. Block = (y, 64-wide x-tile),
// 512 threads = 64 lanes x 8 d-groups (6 d's each).
// ---------------------------------------------------------------------------
__global__ void __launch_bounds__(512)
gather_softmax_kernel(const float* __restrict__ Gx,
                      const float* __restrict__ dvals,
                      float* __restrict__ out) {
    __shared__ float E[D_][64];        // 12 KB: exp values
    __shared__ float red[8][64];       // block max
    __shared__ float sums[3][8][64];   // s, dnum, inum partials

    int t = threadIdx.x;
    int lx = t & 63;
    int dg = t >> 6;                  // 0..7, wave-uniform
    int blk = blockIdx.x;
    int xt = blk % 3;
    int y = blk / 3;
    int x = xt * 64 + lx;
    bool xv = x < W_;
    int xc = min(x, W_ - 1);
    int dbase = dg * 6 - 1;

    float S0[8], S1[8], S2[8];
#pragma unroll
    for (int jj = 0; jj < 8; jj++) {
        float s0 = 0.f, s1 = 0.f, s2 = 0.f;
        int dp = dbase + jj;
        if ((unsigned)dp < (unsigned)D_) {
            const float* g0 = Gx + (size_t)dp * HW_ + xc;
#pragma unroll
            for (int kh = 0; kh < 3; kh++) {
                int yy = y + kh - 1;
                if ((unsigned)yy < (unsigned)H_) {
                    const float* gp = g0 + yy * W_ + (size_t)kh * DHW_;
                    s0 += gp[0];
                    s1 += *(gp + (size_t)3 * DHW_);
                    s2 += *(gp + (size_t)6 * DHW_);
                }
            }
        }
        S0[jj] = s0; S1[jj] = s1; S2[jj] = s2;
    }

    float cost[6];
    float lmax = -1e30f;
#pragma unroll
    for (int j = 0; j < 6; j++) {
        cost[j] = S0[j] + S1[j + 1] + S2[j + 2];
        lmax = fmaxf(lmax, cost[j]);
    }
    red[dg][lx] = lmax;
    __syncthreads();
    float mx = red[0][lx];
#pragma unroll
    for (int g = 1; g < 8; g++) mx = fmaxf(mx, red[g][lx]);

    float s = 0.f, dn = 0.f, din = 0.f;
#pragma unroll
    for (int j = 0; j < 6; j++) {
        int dd = dg * 6 + j;
        float e = __expf(cost[j] - mx);
        E[dd][lx] = e;
        s += e;
        dn = fmaf(e, dvals[dd], dn);
        din = fmaf(e, (float)dd, din);
    }
    sums[0][dg][lx] = s;
    sums[1][dg][lx] = dn;
    sums[2][dg][lx] = din;
    __syncthreads();

    if (dg == 0 && xv) {
        float S = 0.f, DN = 0.f, DI = 0.f;
#pragma unroll
        for (int g = 0; g < 8; g++) {
            S += sums[0][g][lx];
            DN += sums[1][g][lx];
            DI += sums[2][g][lx];
        }
        float invs = 1.f / S;
        float depth = DN * invs;
        int id = (int)(DI * invs);
        id = min(max(id, 0), D_ - 1);
        float conf = 0.f;
#pragma unroll 1
        for (int k = id - 1; k <= id + 2; ++k)
            if (k >= 0 && k < D_) conf += E[k][lx];
        int pix = y * W_ + x;
        out[pix] = depth;
        out[HW_ + pix] = conf * invs;
    }
}

// ---------------------------------------------------------------------------
extern "C" void kernel_launch(void* const* d_in, const int* in_sizes, int n_in,
                              void* d_out, int out_size, void* d_ws, size_t ws_size,
                              hipStream_t stream) {
    const float* ref_feats = (const float*)d_in[0];   // (4,1,32,128,160)
    const float* src_feats = (const float*)d_in[1];   // (4,1,32,128,160)
    const float* proj      = (const float*)d_in[2];   // (1,5,2,4,4)
    const float* dvals     = (const float*)d_in[3];   // (1,48)
    const float* wreg      = (const float*)d_in[5];   // (1,32,3,3,3)
    float* out = (float*)d_out;                       // depth(20480) ++ conf(20480)

    char* ws = (char*)d_ws;
    float* rt   = (float*)ws;                          // 48 floats (pad to 1KB)
    float* srcT = (float*)(ws + 1024);                 // 10.5 MB
    float* refT = srcT + (size_t)4 * HW_ * C_;         // 10.5 MB
    float* Gx   = refT + (size_t)4 * HW_ * C_;         // 9*DHW*4 = 35.4 MB

    transpose2_kernel<<<2561, 256, 0, stream>>>(src_feats, ref_feats, srcT, refT,
                                                proj, rt);
    warp_fold_x_kernel<<<D_ * H_, 256, 0, stream>>>(srcT, refT, rt, dvals, wreg, Gx);
    gather_softmax_kernel<<<3 * H_, 512, 0, stream>>>(Gx, dvals, out);
}

// Round 11
// 206.212 us; speedup vs baseline: 1.1630x; 1.1630x over previous
//
#include <hip/hip_runtime.h>
#include <math.h>

#define H_ 128
#define W_ 160
#define D_ 48
#define C_ 32
#define K27 27
#define HW_ (H_ * W_)
#define DHW_ (D_ * HW_)
#define CHW_ (C_ * HW_)

typedef float f4 __attribute__((ext_vector_type(4)));

// ---------------------------------------------------------------------------
// Projection setup (affine fast path). M(v) = [K(3x3)@E(3x4); 0 0 0 1] is
// affine (E row3 = [0,0,0,1]); inv([[A,b],[0,1]]) = [[A^-1, -A^-1 b],[0,1]].
// For each src view v=1..4 store rot(9)+trans(3) of Mv @ inv(M0).
// ---------------------------------------------------------------------------
__device__ __forceinline__ void build_affine(const float* __restrict__ P, int v,
                                             double A[3][3], double b[3]) {
    const float* E = P + v * 32;
    const float* K = P + v * 32 + 16;
    for (int i = 0; i < 3; i++) {
        for (int j = 0; j < 3; j++) {
            double s = 0.0;
            for (int k = 0; k < 3; k++) s += (double)K[i * 4 + k] * (double)E[k * 4 + j];
            A[i][j] = s;
        }
        double s = 0.0;
        for (int k = 0; k < 3; k++) s += (double)K[i * 4 + k] * (double)E[k * 4 + 3];
        b[i] = s;
    }
}

__device__ void do_proj(const float* __restrict__ P, float* __restrict__ rt) {
    double A0[3][3], b0[3];
    build_affine(P, 0, A0, b0);
    double det = A0[0][0] * (A0[1][1] * A0[2][2] - A0[1][2] * A0[2][1])
               - A0[0][1] * (A0[1][0] * A0[2][2] - A0[1][2] * A0[2][0])
               + A0[0][2] * (A0[1][0] * A0[2][1] - A0[1][1] * A0[2][0]);
    double id = 1.0 / det;
    double Ai[3][3];
    Ai[0][0] = (A0[1][1] * A0[2][2] - A0[1][2] * A0[2][1]) * id;
    Ai[0][1] = (A0[0][2] * A0[2][1] - A0[0][1] * A0[2][2]) * id;
    Ai[0][2] = (A0[0][1] * A0[1][2] - A0[0][2] * A0[1][1]) * id;
    Ai[1][0] = (A0[1][2] * A0[2][0] - A0[1][0] * A0[2][2]) * id;
    Ai[1][1] = (A0[0][0] * A0[2][2] - A0[0][2] * A0[2][0]) * id;
    Ai[1][2] = (A0[0][2] * A0[1][0] - A0[0][0] * A0[1][2]) * id;
    Ai[2][0] = (A0[1][0] * A0[2][1] - A0[1][1] * A0[2][0]) * id;
    Ai[2][1] = (A0[0][1] * A0[2][0] - A0[0][0] * A0[2][1]) * id;
    Ai[2][2] = (A0[0][0] * A0[1][1] - A0[0][1] * A0[1][0]) * id;
    double t0[3];
    for (int i = 0; i < 3; i++)
        t0[i] = -(Ai[i][0] * b0[0] + Ai[i][1] * b0[1] + Ai[i][2] * b0[2]);

    for (int v = 1; v < 5; ++v) {
        double Av[3][3], bv[3];
        build_affine(P, v, Av, bv);
        float* o = rt + (v - 1) * 12;
        for (int i = 0; i < 3; i++) {
            for (int j = 0; j < 3; j++) {
                double s = Av[i][0] * Ai[0][j] + Av[i][1] * Ai[1][j] + Av[i][2] * Ai[2][j];
                o[i * 3 + j] = (float)s;
            }
            o[9 + i] = (float)(Av[i][0] * t0[0] + Av[i][1] * t0[1] +
                               Av[i][2] * t0[2] + bv[i]);
        }
    }
}

// ---------------------------------------------------------------------------
// Kernel 1: LDS-staged transpose [4][C][HW] -> [4][HW][C] for both tensors,
// fully coalesced reads AND writes. 2560 tile-blocks + 1 proj block.
// ---------------------------------------------------------------------------
__global__ void __launch_bounds__(256)
transpose2_kernel(const float* __restrict__ sf, const float* __restrict__ rf,
                  float* __restrict__ so, float* __restrict__ ro,
                  const float* __restrict__ P, float* __restrict__ rt) {
    int blk = blockIdx.x;
    if (blk >= 2560) {
        if (threadIdx.x == 0) do_proj(P, rt);
        return;
    }
    __shared__ float tile[C_][65];
    int t = threadIdx.x;
    int tv = blk / 320;            // 0..7: tensor(2) x view(4)
    int tileI = blk % 320;
    int pixbase = tileI * 64;
    const float* in = (tv < 4) ? sf : rf;
    float* out = (tv < 4) ? so : ro;
    int v = tv & 3;

    int pix = t & 63;
    int cbase = (t >> 6) * 8;
#pragma unroll
    for (int cc = 0; cc < 8; cc++) {
        int c = cbase + cc;
        tile[c][pix] = in[(size_t)v * CHW_ + c * HW_ + pixbase + pix];
    }
    __syncthreads();

    float* obase = out + ((size_t)v * HW_ + pixbase) * C_;
#pragma unroll
    for (int r = 0; r < 2; r++) {
        int i = r * 256 + t;       // f4 index 0..511
        int wpix = i >> 3;
        int c0 = (i & 7) * 4;
        f4 w = {tile[c0][wpix], tile[c0 + 1][wpix], tile[c0 + 2][wpix],
                tile[c0 + 3][wpix]};
        *(f4*)(obase + (size_t)wpix * C_ + c0) = w;
    }
}

// ---------------------------------------------------------------------------
// Kernel 2: one image row (d,y) per block; 3 batches of 64 positions
// (62 outputs + 2 halo each). Small LDS (15.2 KB); NO min-waves bound
// (round 10: (256,8) forced VGPR 32 -> 120MB scratch spills, net loss).
//   phase 1: bilinear+ref blend for 8 channels -> accT LDS
//   phase 2: fold channels through conv weights (wave-uniform taps, SGPR
//            weights, 4 partial sums) -> gLDS[27][64]
//   phase 3: per-batch x-shift-add -> 9 planes Gx
// ---------------------------------------------------------------------------
__global__ void __launch_bounds__(256)
warp_fold_x_kernel(const float* __restrict__ srcT,
                   const float* __restrict__ refT,
                   const float* __restrict__ rt,
                   const float* __restrict__ dvals,
                   const float* __restrict__ wreg,
                   float* __restrict__ Gx) {
    __shared__ float accT[8][64][4];   // 8 KB
    __shared__ float gLDS[K27][64];    // 6.9 KB

    int t = threadIdx.x;
    int vox = t >> 2;          // 0..63
    int cgrp = t & 3;          // channel group
    int blk = blockIdx.x;      // 0..6143
    int d = blk >> 7;
    int y = blk & 127;
    float depth = dvals[d];
    float yf = (float)y;
    int rowbase = d * HW_ + y * W_;

#pragma unroll 1
    for (int b = 0; b < 3; b++) {
        int xbase = b * 62 - 1;
        int x = xbase + vox;              // -1 .. 186

        f4 acc0 = (f4){0.f, 0.f, 0.f, 0.f};
        f4 acc1 = (f4){0.f, 0.f, 0.f, 0.f};

        if (x >= 0 && x < W_) {
            float xf = (float)x;
            int pix = y * W_ + x;
#pragma unroll 2
            for (int v = 0; v < 4; v++) {
                const float* m = rt + v * 12;
                float px = fmaf(fmaf(m[0], xf, fmaf(m[1], yf, m[2])), depth, m[9]);
                float py = fmaf(fmaf(m[3], xf, fmaf(m[4], yf, m[5])), depth, m[10]);
                float pz = fmaf(fmaf(m[6], xf, fmaf(m[7], yf, m[8])), depth, m[11]);
                float iz = 1.f / pz;
                px *= iz;
                py *= iz;
                float x0f = floorf(px), y0f = floorf(py);
                float wx = px - x0f, wy = py - y0f;
                int x0 = (int)x0f, y0 = (int)y0f;
                int x1 = x0 + 1, y1 = y0 + 1;

                float w00 = (1.f - wx) * (1.f - wy);
                float w10 = wx * (1.f - wy);
                float w01 = (1.f - wx) * wy;
                float w11 = wx * wy;
                bool vx0 = (x0 >= 0) && (x0 < W_);
                bool vx1 = (x1 >= 0) && (x1 < W_);
                bool vy0 = (y0 >= 0) && (y0 < H_);
                bool vy1 = (y1 >= 0) && (y1 < H_);
                if (!(vx0 && vy0)) w00 = 0.f;
                if (!(vx1 && vy0)) w10 = 0.f;
                if (!(vx0 && vy1)) w01 = 0.f;
                if (!(vx1 && vy1)) w11 = 0.f;
                int cx0 = min(max(x0, 0), W_ - 1);
                int cx1 = min(max(x1, 0), W_ - 1);
                int cy0 = min(max(y0, 0), H_ - 1);
                int cy1 = min(max(y1, 0), H_ - 1);

                const float* sv = srcT + (size_t)v * HW_ * C_ + cgrp * 8;
                const f4* p00 = (const f4*)(sv + (cy0 * W_ + cx0) * C_);
                const f4* p10 = (const f4*)(sv + (cy0 * W_ + cx1) * C_);
                const f4* p01 = (const f4*)(sv + (cy1 * W_ + cx0) * C_);
                const f4* p11 = (const f4*)(sv + (cy1 * W_ + cx1) * C_);
                const f4* pr  = (const f4*)(refT + ((size_t)v * HW_ + pix) * C_ + cgrp * 8);

                f4 a00 = p00[0], b00 = p00[1];
                f4 a10 = p10[0], b10 = p10[1];
                f4 a01 = p01[0], b01 = p01[1];
                f4 a11 = p11[0], b11 = p11[1];
                f4 r0 = pr[0],  r1 = pr[1];

                f4 sv0 = a00 * w00 + a10 * w10 + a01 * w01 + a11 * w11;
                f4 sv1 = b00 * w00 + b10 * w10 + b01 * w01 + b11 * w11;
                acc0 += r0 * sv0;
                acc1 += r1 * sv1;
            }
            acc0 *= 0.25f;
            acc1 *= 0.25f;
        }

        int cq0 = cgrp * 2;
        *(f4*)&accT[cq0][vox][0] = acc0;
        *(f4*)&accT[cq0 + 1][vox][0] = acc1;
        __syncthreads();

        // ---- phase 2: fold channels, wave-uniform tap ranges ----
        int fvox = t & 63;
        int kg = t >> 6;                   // 0..3
        float av[C_];
#pragma unroll
        for (int cq = 0; cq < 8; cq++)
            *(f4*)&av[cq * 4] = *(const f4*)&accT[cq][fvox][0];

        int kstart = kg * 7;
        int kend = min(kstart + 7, K27);
#pragma unroll 1
        for (int k = kstart; k < kend; k++) {
            int ku = __builtin_amdgcn_readfirstlane(k);
            const float* wk = wreg + ku;
            float g0 = 0.f, g1 = 0.f, g2 = 0.f, g3 = 0.f;
#pragma unroll
            for (int cq = 0; cq < 8; cq++) {
                g0 = fmaf(wk[(cq * 4 + 0) * K27], av[cq * 4 + 0], g0);
                g1 = fmaf(wk[(cq * 4 + 1) * K27], av[cq * 4 + 1], g1);
                g2 = fmaf(wk[(cq * 4 + 2) * K27], av[cq * 4 + 2], g2);
                g3 = fmaf(wk[(cq * 4 + 3) * K27], av[cq * 4 + 3], g3);
            }
            gLDS[ku][fvox] = (g0 + g1) + (g2 + g3);
        }
        __syncthreads();

        // ---- phase 3: x-shift-add for this batch -> 9 planes ----
        int xout = b * 62 + t;            // t < 62 lanes participate
        if (t < 62 && xout < W_) {
#pragma unroll
            for (int j = 0; j < 9; j++) {
                float s = gLDS[j * 3 + 0][t] + gLDS[j * 3 + 1][t + 1] +
                          gLDS[j * 3 + 2][t + 2];
                Gx[(size_t)j * DHW_ + rowbase + xout] = s;
            }
        }
        __syncthreads();   // gLDS/accT reuse next batch
    }
}

// ---------------------------------------------------------------------------
// Kernel 3 (fused): gather 9 Gx planes over (d,y) shifts + softmax over D +
// expected depth + windowed confidence. Block = (y, 64-wide x-tile),
// 512 threads = 64 lanes x 8 d-groups (6 d's each).
// ---------------------------------------------------------------------------
__global__ void __launch_bounds__(512)
gather_softmax_kernel(const float* __restrict__ Gx,
                      const float* __restrict__ dvals,
                      float* __restrict__ out) {
    __shared__ float E[D_][64];        // 12 KB: exp values
    __shared__ float red[8][64];       // block max
    __shared__ float sums[3][8][64];   // s, dnum, inum partials

    int t = threadIdx.x;
    int lx = t & 63;
    int dg = t >> 6;                  // 0..7, wave-uniform
    int blk = blockIdx.x;
    int xt = blk % 3;
    int y = blk / 3;
    int x = xt * 64 + lx;
    bool xv = x < W_;
    int xc = min(x, W_ - 1);
    int dbase = dg * 6 - 1;

    float S0[8], S1[8], S2[8];
#pragma unroll
    for (int jj = 0; jj < 8; jj++) {
        float s0 = 0.f, s1 = 0.f, s2 = 0.f;
        int dp = dbase + jj;
        if ((unsigned)dp < (unsigned)D_) {
            const float* g0 = Gx + (size_t)dp * HW_ + xc;
#pragma unroll
            for (int kh = 0; kh < 3; kh++) {
                int yy = y + kh - 1;
                if ((unsigned)yy < (unsigned)H_) {
                    const float* gp = g0 + yy * W_ + (size_t)kh * DHW_;
                    s0 += gp[0];
                    s1 += *(gp + (size_t)3 * DHW_);
                    s2 += *(gp + (size_t)6 * DHW_);
                }
            }
        }
        S0[jj] = s0; S1[jj] = s1; S2[jj] = s2;
    }

    float cost[6];
    float lmax = -1e30f;
#pragma unroll
    for (int j = 0; j < 6; j++) {
        cost[j] = S0[j] + S1[j + 1] + S2[j + 2];
        lmax = fmaxf(lmax, cost[j]);
    }
    red[dg][lx] = lmax;
    __syncthreads();
    float mx = red[0][lx];
#pragma unroll
    for (int g = 1; g < 8; g++) mx = fmaxf(mx, red[g][lx]);

    float s = 0.f, dn = 0.f, din = 0.f;
#pragma unroll
    for (int j = 0; j < 6; j++) {
        int dd = dg * 6 + j;
        float e = __expf(cost[j] - mx);
        E[dd][lx] = e;
        s += e;
        dn = fmaf(e, dvals[dd], dn);
        din = fmaf(e, (float)dd, din);
    }
    sums[0][dg][lx] = s;
    sums[1][dg][lx] = dn;
    sums[2][dg][lx] = din;
    __syncthreads();

    if (dg == 0 && xv) {
        float S = 0.f, DN = 0.f, DI = 0.f;
#pragma unroll
        for (int g = 0; g < 8; g++) {
            S += sums[0][g][lx];
            DN += sums[1][g][lx];
            DI += sums[2][g][lx];
        }
        float invs = 1.f / S;
        float depth = DN * invs;
        int id = (int)(DI * invs);
        id = min(max(id, 0), D_ - 1);
        float conf = 0.f;
#pragma unroll 1
        for (int k = id - 1; k <= id + 2; ++k)
            if (k >= 0 && k < D_) conf += E[k][lx];
        int pix = y * W_ + x;
        out[pix] = depth;
        out[HW_ + pix] = conf * invs;
    }
}

// ---------------------------------------------------------------------------
extern "C" void kernel_launch(void* const* d_in, const int* in_sizes, int n_in,
                              void* d_out, int out_size, void* d_ws, size_t ws_size,
                              hipStream_t stream) {
    const float* ref_feats = (const float*)d_in[0];   // (4,1,32,128,160)
    const float* src_feats = (const float*)d_in[1];   // (4,1,32,128,160)
    const float* proj      = (const float*)d_in[2];   // (1,5,2,4,4)
    const float* dvals     = (const float*)d_in[3];   // (1,48)
    const float* wreg      = (const float*)d_in[5];   // (1,32,3,3,3)
    float* out = (float*)d_out;                       // depth(20480) ++ conf(20480)

    char* ws = (char*)d_ws;
    float* rt   = (float*)ws;                          // 48 floats (pad to 1KB)
    float* srcT = (float*)(ws + 1024);                 // 10.5 MB
    float* refT = srcT + (size_t)4 * HW_ * C_;         // 10.5 MB
    float* Gx   = refT + (size_t)4 * HW_ * C_;         // 9*DHW*4 = 35.4 MB

    transpose2_kernel<<<2561, 256, 0, stream>>>(src_feats, ref_feats, srcT, refT,
                                                proj, rt);
    warp_fold_x_kernel<<<D_ * H_, 256, 0, stream>>>(srcT, refT, rt, dvals, wreg, Gx);
    gather_softmax_kernel<<<3 * H_, 512, 0, stream>>>(Gx, dvals, out);
}

// Round 13
// 180.530 us; speedup vs baseline: 1.3284x; 1.1423x over previous
//
#include <hip/hip_runtime.h>
#include <math.h>

#define H_ 128
#define W_ 160
#define D_ 48
#define C_ 32
#define K27 27
#define HW_ (H_ * W_)
#define DHW_ (D_ * HW_)
#define CHW_ (C_ * HW_)

typedef float f4 __attribute__((ext_vector_type(4)));
typedef _Float16 h8 __attribute__((ext_vector_type(8)));

// ---------------------------------------------------------------------------
// Projection setup (affine fast path): M = [K3x3 @ E3x4; 0 0 0 1] is affine;
// inv([[A,b],[0,1]]) = [[A^-1, -A^-1 b],[0,1]]. Store rot+trans of Mv@inv(M0).
// ---------------------------------------------------------------------------
__device__ __forceinline__ void build_affine(const float* __restrict__ P, int v,
                                             double A[3][3], double b[3]) {
    const float* E = P + v * 32;
    const float* K = P + v * 32 + 16;
    for (int i = 0; i < 3; i++) {
        for (int j = 0; j < 3; j++) {
            double s = 0.0;
            for (int k = 0; k < 3; k++) s += (double)K[i * 4 + k] * (double)E[k * 4 + j];
            A[i][j] = s;
        }
        double s = 0.0;
        for (int k = 0; k < 3; k++) s += (double)K[i * 4 + k] * (double)E[k * 4 + 3];
        b[i] = s;
    }
}

__device__ void do_proj(const float* __restrict__ P, float* __restrict__ rt) {
    double A0[3][3], b0[3];
    build_affine(P, 0, A0, b0);
    double det = A0[0][0] * (A0[1][1] * A0[2][2] - A0[1][2] * A0[2][1])
               - A0[0][1] * (A0[1][0] * A0[2][2] - A0[1][2] * A0[2][0])
               + A0[0][2] * (A0[1][0] * A0[2][1] - A0[1][1] * A0[2][0]);
    double id = 1.0 / det;
    double Ai[3][3];
    Ai[0][0] = (A0[1][1] * A0[2][2] - A0[1][2] * A0[2][1]) * id;
    Ai[0][1] = (A0[0][2] * A0[2][1] - A0[0][1] * A0[2][2]) * id;
    Ai[0][2] = (A0[0][1] * A0[1][2] - A0[0][2] * A0[1][1]) * id;
    Ai[1][0] = (A0[1][2] * A0[2][0] - A0[1][0] * A0[2][2]) * id;
    Ai[1][1] = (A0[0][0] * A0[2][2] - A0[0][2] * A0[2][0]) * id;
    Ai[1][2] = (A0[0][2] * A0[1][0] - A0[0][0] * A0[1][2]) * id;
    Ai[2][0] = (A0[1][0] * A0[2][1] - A0[1][1] * A0[2][0]) * id;
    Ai[2][1] = (A0[0][1] * A0[2][0] - A0[0][0] * A0[2][1]) * id;
    Ai[2][2] = (A0[0][0] * A0[1][1] - A0[0][1] * A0[1][0]) * id;
    double t0[3];
    for (int i = 0; i < 3; i++)
        t0[i] = -(Ai[i][0] * b0[0] + Ai[i][1] * b0[1] + Ai[i][2] * b0[2]);

    for (int v = 1; v < 5; ++v) {
        double Av[3][3], bv[3];
        build_affine(P, v, Av, bv);
        float* o = rt + (v - 1) * 12;
        for (int i = 0; i < 3; i++) {
            for (int j = 0; j < 3; j++) {
                double s = Av[i][0] * Ai[0][j] + Av[i][1] * Ai[1][j] + Av[i][2] * Ai[2][j];
                o[i * 3 + j] = (float)s;
            }
            o[9 + i] = (float)(Av[i][0] * t0[0] + Av[i][1] * t0[1] +
                               Av[i][2] * t0[2] + bv[i]);
        }
    }
}

// ---------------------------------------------------------------------------
// Kernel 1: LDS-staged transpose. src -> fp16 channels-last (5.2 MB),
// ref -> fp32 channels-last. Coalesced reads and writes. +1 proj block.
// ---------------------------------------------------------------------------
__global__ void __launch_bounds__(256)
transpose2_kernel(const float* __restrict__ sf, const float* __restrict__ rf,
                  _Float16* __restrict__ so, float* __restrict__ ro,
                  const float* __restrict__ P, float* __restrict__ rt) {
    int blk = blockIdx.x;
    if (blk >= 2560) {
        if (threadIdx.x == 0) do_proj(P, rt);
        return;
    }
    __shared__ float tile[C_][65];
    int t = threadIdx.x;
    int tv = blk / 320;            // 0..7: tensor(2) x view(4)
    int tileI = blk % 320;
    int pixbase = tileI * 64;
    const float* in = (tv < 4) ? sf : rf;
    int v = tv & 3;

    int pix = t & 63;
    int cbase = (t >> 6) * 8;
#pragma unroll
    for (int cc = 0; cc < 8; cc++) {
        int c = cbase + cc;
        tile[c][pix] = in[(size_t)v * CHW_ + c * HW_ + pixbase + pix];
    }
    __syncthreads();

    if (tv < 4) {
        // fp16 output: thread -> (pixel = t>>2, 8-channel chunk = (t&3)*8)
        int wpix = t >> 2;
        int c0 = (t & 3) * 8;
        h8 w;
#pragma unroll
        for (int j = 0; j < 8; j++) w[j] = (_Float16)tile[c0 + j][wpix];
        *(h8*)(so + ((size_t)v * HW_ + pixbase + wpix) * C_ + c0) = w;
    } else {
        float* obase = ro + ((size_t)v * HW_ + pixbase) * C_;
#pragma unroll
        for (int r = 0; r < 2; r++) {
            int i = r * 256 + t;
            int wpix = i >> 3;
            int c0 = (i & 7) * 4;
            f4 w = {tile[c0][wpix], tile[c0 + 1][wpix], tile[c0 + 2][wpix],
                    tile[c0 + 3][wpix]};
            *(f4*)(obase + (size_t)wpix * C_ + c0) = w;
        }
    }
}

// ---------------------------------------------------------------------------
// Kernel 2: one image row (d,y) per block; 3 batches of 64 positions
// (62 outputs + 2 halo). fp16 src: 1 b128 per corner (8ch), packed-half
// blend (v_pk_fma_f16), fp32 accumulate against fp32 ref.
//   phase 1: bilinear+ref blend for 8 channels -> accT LDS
//   phase 2: fold channels through conv weights (wave-uniform taps) -> gLDS
//   phase 3: per-batch x-shift-add -> 9 planes Gx
// ---------------------------------------------------------------------------
__global__ void __launch_bounds__(256)
warp_fold_x_kernel(const _Float16* __restrict__ srcH,
                   const float* __restrict__ refT,
                   const float* __restrict__ rt,
                   const float* __restrict__ dvals,
                   const float* __restrict__ wreg,
                   float* __restrict__ Gx) {
    __shared__ float accT[8][64][4];   // 8 KB
    __shared__ float gLDS[K27][64];    // 6.9 KB

    int t = threadIdx.x;
    int vox = t >> 2;          // 0..63
    int cgrp = t & 3;          // channel group
    int blk = blockIdx.x;      // 0..6143
    int d = blk >> 7;
    int y = blk & 127;
    float depth = dvals[d];
    float yf = (float)y;
    int rowbase = d * HW_ + y * W_;

#pragma unroll 1
    for (int b = 0; b < 3; b++) {
        int xbase = b * 62 - 1;
        int x = xbase + vox;              // -1 .. 186

        f4 acc0 = (f4){0.f, 0.f, 0.f, 0.f};
        f4 acc1 = (f4){0.f, 0.f, 0.f, 0.f};

        if (x >= 0 && x < W_) {
            float xf = (float)x;
            int pix = y * W_ + x;
#pragma unroll 2
            for (int v = 0; v < 4; v++) {
                const float* m = rt + v * 12;
                float px = fmaf(fmaf(m[0], xf, fmaf(m[1], yf, m[2])), depth, m[9]);
                float py = fmaf(fmaf(m[3], xf, fmaf(m[4], yf, m[5])), depth, m[10]);
                float pz = fmaf(fmaf(m[6], xf, fmaf(m[7], yf, m[8])), depth, m[11]);
                float iz = 1.f / pz;
                px *= iz;
                py *= iz;
                float x0f = floorf(px), y0f = floorf(py);
                float wx = px - x0f, wy = py - y0f;
                int x0 = (int)x0f, y0 = (int)y0f;
                int x1 = x0 + 1, y1 = y0 + 1;

                float w00 = (1.f - wx) * (1.f - wy);
                float w10 = wx * (1.f - wy);
                float w01 = (1.f - wx) * wy;
                float w11 = wx * wy;
                bool vx0 = (x0 >= 0) && (x0 < W_);
                bool vx1 = (x1 >= 0) && (x1 < W_);
                bool vy0 = (y0 >= 0) && (y0 < H_);
                bool vy1 = (y1 >= 0) && (y1 < H_);
                if (!(vx0 && vy0)) w00 = 0.f;
                if (!(vx1 && vy0)) w10 = 0.f;
                if (!(vx0 && vy1)) w01 = 0.f;
                if (!(vx1 && vy1)) w11 = 0.f;
                int cx0 = min(max(x0, 0), W_ - 1);
                int cx1 = min(max(x1, 0), W_ - 1);
                int cy0 = min(max(y0, 0), H_ - 1);
                int cy1 = min(max(y1, 0), H_ - 1);

                const _Float16* sv = srcH + (size_t)v * HW_ * C_ + cgrp * 8;
                h8 a00 = *(const h8*)(sv + (cy0 * W_ + cx0) * C_);
                h8 a10 = *(const h8*)(sv + (cy0 * W_ + cx1) * C_);
                h8 a01 = *(const h8*)(sv + (cy1 * W_ + cx0) * C_);
                h8 a11 = *(const h8*)(sv + (cy1 * W_ + cx1) * C_);
                const f4* pr = (const f4*)(refT + ((size_t)v * HW_ + pix) * C_ + cgrp * 8);
                f4 r0 = pr[0], r1 = pr[1];

                _Float16 h00 = (_Float16)w00, h10 = (_Float16)w10;
                _Float16 h01 = (_Float16)w01, h11 = (_Float16)w11;
                h8 svh = a00 * h00 + a10 * h10 + a01 * h01 + a11 * h11;

                f4 lo = {(float)svh[0], (float)svh[1], (float)svh[2], (float)svh[3]};
                f4 hi = {(float)svh[4], (float)svh[5], (float)svh[6], (float)svh[7]};
                acc0 += r0 * lo;
                acc1 += r1 * hi;
            }
            acc0 *= 0.25f;
            acc1 *= 0.25f;
        }

        int cq0 = cgrp * 2;
        *(f4*)&accT[cq0][vox][0] = acc0;
        *(f4*)&accT[cq0 + 1][vox][0] = acc1;
        __syncthreads();

        // ---- phase 2: fold channels, wave-uniform tap ranges ----
        int fvox = t & 63;
        int kg = t >> 6;                   // 0..3
        float av[C_];
#pragma unroll
        for (int cq = 0; cq < 8; cq++)
            *(f4*)&av[cq * 4] = *(const f4*)&accT[cq][fvox][0];

        int kstart = kg * 7;
        int kend = min(kstart + 7, K27);
#pragma unroll 1
        for (int k = kstart; k < kend; k++) {
            int ku = __builtin_amdgcn_readfirstlane(k);
            const float* wk = wreg + ku;
            float g0 = 0.f, g1 = 0.f, g2 = 0.f, g3 = 0.f;
#pragma unroll
            for (int cq = 0; cq < 8; cq++) {
                g0 = fmaf(wk[(cq * 4 + 0) * K27], av[cq * 4 + 0], g0);
                g1 = fmaf(wk[(cq * 4 + 1) * K27], av[cq * 4 + 1], g1);
                g2 = fmaf(wk[(cq * 4 + 2) * K27], av[cq * 4 + 2], g2);
                g3 = fmaf(wk[(cq * 4 + 3) * K27], av[cq * 4 + 3], g3);
            }
            gLDS[ku][fvox] = (g0 + g1) + (g2 + g3);
        }
        __syncthreads();

        // ---- phase 3: x-shift-add for this batch -> 9 planes ----
        int xout = b * 62 + t;            // t < 62 lanes participate
        if (t < 62 && xout < W_) {
#pragma unroll
            for (int j = 0; j < 9; j++) {
                float s = gLDS[j * 3 + 0][t] + gLDS[j * 3 + 1][t + 1] +
                          gLDS[j * 3 + 2][t + 2];
                Gx[(size_t)j * DHW_ + rowbase + xout] = s;
            }
        }
        __syncthreads();   // gLDS/accT reuse next batch
    }
}

// ---------------------------------------------------------------------------
// Kernel 3 (fused): gather 9 Gx planes over (d,y) shifts + softmax over D +
// expected depth + windowed confidence. Block = (y, 64-wide x-tile),
// 512 threads = 64 lanes x 8 d-groups (6 d's each).
// ---------------------------------------------------------------------------
__global__ void __launch_bounds__(512)
gather_softmax_kernel(const float* __restrict__ Gx,
                      const float* __restrict__ dvals,
                      float* __restrict__ out) {
    __shared__ float E[D_][64];        // 12 KB: exp values
    __shared__ float red[8][64];       // block max
    __shared__ float sums[3][8][64];   // s, dnum, inum partials

    int t = threadIdx.x;
    int lx = t & 63;
    int dg = t >> 6;                  // 0..7, wave-uniform
    int blk = blockIdx.x;
    int xt = blk % 3;
    int y = blk / 3;
    int x = xt * 64 + lx;
    bool xv = x < W_;
    int xc = min(x, W_ - 1);
    int dbase = dg * 6 - 1;

    float S0[8], S1[8], S2[8];
#pragma unroll
    for (int jj = 0; jj < 8; jj++) {
        float s0 = 0.f, s1 = 0.f, s2 = 0.f;
        int dp = dbase + jj;
        if ((unsigned)dp < (unsigned)D_) {
            const float* g0 = Gx + (size_t)dp * HW_ + xc;
#pragma unroll
            for (int kh = 0; kh < 3; kh++) {
                int yy = y + kh - 1;
                if ((unsigned)yy < (unsigned)H_) {
                    const float* gp = g0 + yy * W_ + (size_t)kh * DHW_;
                    s0 += gp[0];
                    s1 += *(gp + (size_t)3 * DHW_);
                    s2 += *(gp + (size_t)6 * DHW_);
                }
            }
        }
        S0[jj] = s0; S1[jj] = s1; S2[jj] = s2;
    }

    float cost[6];
    float lmax = -1e30f;
#pragma unroll
    for (int j = 0; j < 6; j++) {
        cost[j] = S0[j] + S1[j + 1] + S2[j + 2];
        lmax = fmaxf(lmax, cost[j]);
    }
    red[dg][lx] = lmax;
    __syncthreads();
    float mx = red[0][lx];
#pragma unroll
    for (int g = 1; g < 8; g++) mx = fmaxf(mx, red[g][lx]);

    float s = 0.f, dn = 0.f, din = 0.f;
#pragma unroll
    for (int j = 0; j < 6; j++) {
        int dd = dg * 6 + j;
        float e = __expf(cost[j] - mx);
        E[dd][lx] = e;
        s += e;
        dn = fmaf(e, dvals[dd], dn);
        din = fmaf(e, (float)dd, din);
    }
    sums[0][dg][lx] = s;
    sums[1][dg][lx] = dn;
    sums[2][dg][lx] = din;
    __syncthreads();

    if (dg == 0 && xv) {
        float S = 0.f, DN = 0.f, DI = 0.f;
#pragma unroll
        for (int g = 0; g < 8; g++) {
            S += sums[0][g][lx];
            DN += sums[1][g][lx];
            DI += sums[2][g][lx];
        }
        float invs = 1.f / S;
        float depth = DN * invs;
        int id = (int)(DI * invs);
        id = min(max(id, 0), D_ - 1);
        float conf = 0.f;
#pragma unroll 1
        for (int k = id - 1; k <= id + 2; ++k)
            if (k >= 0 && k < D_) conf += E[k][lx];
        int pix = y * W_ + x;
        out[pix] = depth;
        out[HW_ + pix] = conf * invs;
    }
}

// ---------------------------------------------------------------------------
extern "C" void kernel_launch(void* const* d_in, const int* in_sizes, int n_in,
                              void* d_out, int out_size, void* d_ws, size_t ws_size,
                              hipStream_t stream) {
    const float* ref_feats = (const float*)d_in[0];   // (4,1,32,128,160)
    const float* src_feats = (const float*)d_in[1];   // (4,1,32,128,160)
    const float* proj      = (const float*)d_in[2];   // (1,5,2,4,4)
    const float* dvals     = (const float*)d_in[3];   // (1,48)
    const float* wreg      = (const float*)d_in[5];   // (1,32,3,3,3)
    float* out = (float*)d_out;                       // depth(20480) ++ conf(20480)

    char* ws = (char*)d_ws;
    float* rt    = (float*)ws;                             // 48 floats (1KB pad)
    _Float16* srcH = (_Float16*)(ws + 1024);               // 4*HW*32*2 = 5.25 MB
    float* refT  = (float*)(ws + 1024 + (size_t)4 * HW_ * C_ * 2);   // 10.5 MB
    float* Gx    = refT + (size_t)4 * HW_ * C_;            // 9*DHW*4 = 35.4 MB

    transpose2_kernel<<<2561, 256, 0, stream>>>(src_feats, ref_feats, srcH, refT,
                                                proj, rt);
    warp_fold_x_kernel<<<D_ * H_, 256, 0, stream>>>(srcH, refT, rt, dvals, wreg, Gx);
    gather_softmax_kernel<<<3 * H_, 512, 0, stream>>>(Gx, dvals, out);
}